// Round 11
// baseline (208.808 us; speedup 1.0000x reference)
//
#include <hip/hip_runtime.h>
#include <math.h>

// Problem constants (from reference)
#define N_G   60000
#define N_D   40000
#define NTOT  100000          // N_G + N_D
#define DIM   64
#define E_EDGES 1600000
#define B_BATCH 4096
#define K_NEG   1
#define DECAY_F 1e-4f

#define BIN_SHIFT 9
#define BIN_SIZE (1 << BIN_SHIFT)                   // 512 rows per bin
#define NBIN ((NTOT + BIN_SIZE - 1) >> BIN_SHIFT)   // 196 bins
#define SCAT_BLOCKS 1000
#define EPB (E_EDGES / SCAT_BLOCKS)                 // 1600 edges per block
#define NBB (NBIN * SCAT_BLOCKS)                    // 196000 (block,bin) counters
#define NB2 ((NBB + 1023) / 1024)                   // 192 scan blocks

// 4-byte edge record: (val_bf15 << 17) | col.  val >= 0 so sign bit implicit 0.
__device__ __forceinline__ float rec_val(unsigned rec) {
    return __uint_as_float((rec >> 17) << 16);
}

// ---------------------------------------------------------------------------
// conv_q: quantize concat(ge,de) to int8 per-row-scale. One wave per row.
// lane = dim. q = round(x*127/rowmax)+128 stored as u8; scl[row] = rowmax/127.
// ---------------------------------------------------------------------------
__global__ void __launch_bounds__(256) conv_q(
        const float* __restrict__ ge, const float* __restrict__ de,
        unsigned char* __restrict__ rawq, float* __restrict__ scl) {
    int gtid = blockIdx.x * blockDim.x + threadIdx.x;
    int row  = gtid >> 6;
    int lane = gtid & 63;
    if (row >= NTOT) return;
    float x = (row < N_G) ? ge[(size_t)row * DIM + lane]
                          : de[(size_t)(row - N_G) * DIM + lane];
    float m = fabsf(x);
    #pragma unroll
    for (int off = 1; off < 64; off <<= 1) m = fmaxf(m, __shfl_xor(m, off));
    float inv = (m > 0.0f) ? 127.0f / m : 0.0f;
    unsigned q = (unsigned)fmaf(x, inv, 128.5f);     // [1,255], 128 == 0
    rawq[(size_t)row * DIM + lane] = (unsigned char)q;
    if (lane == 0) scl[row] = m * (1.0f / 127.0f);
}

// ---------------------------------------------------------------------------
// CSR build — zero global atomics. hist1 -> scan(bbcnt) -> binscatter -> binfinal
// ---------------------------------------------------------------------------
__global__ void __launch_bounds__(256) k_hist1(const int* __restrict__ arow,
                                               int* __restrict__ bbcnt) {
    __shared__ int cnt[NBIN];
    int t = threadIdx.x;
    for (int i = t; i < NBIN; i += 256) cnt[i] = 0;
    __syncthreads();
    int s = blockIdx.x * EPB, e = s + EPB;
    for (int i = s + t; i < e; i += 256)
        atomicAdd(&cnt[arow[i] >> BIN_SHIFT], 1);    // LDS atomic
    __syncthreads();
    for (int i = t; i < NBIN; i += 256)
        bbcnt[i * SCAT_BLOCKS + blockIdx.x] = cnt[i];
}

__global__ void k_scan1g(const int* __restrict__ in, int* __restrict__ excl,
                         int* __restrict__ blocksum) {
    int gid  = blockIdx.x * 1024 + threadIdx.x;
    int lane = threadIdx.x & 63;
    int wid  = threadIdx.x >> 6;           // 16 waves
    int v = (gid < NBB) ? in[gid] : 0;
    int x = v;
    #pragma unroll
    for (int off = 1; off < 64; off <<= 1) {
        int y = __shfl_up(x, off);
        if (lane >= off) x += y;
    }
    __shared__ int wsum[16];
    if (lane == 63) wsum[wid] = x;
    __syncthreads();
    if (wid == 0) {
        int w = (lane < 16) ? wsum[lane] : 0;
        #pragma unroll
        for (int off = 1; off < 16; off <<= 1) {
            int y = __shfl_up(w, off);
            if (lane >= off) w += y;
        }
        if (lane < 16) wsum[lane] = w;
    }
    __syncthreads();
    int woff = (wid == 0) ? 0 : wsum[wid - 1];
    int incl = x + woff;
    if (gid < NBB) excl[gid] = incl - v;
    if (threadIdx.x == 1023) blocksum[blockIdx.x] = incl;
}

// scan of up to 256 block sums (NB2 = 192)
__global__ void k_scan2g(const int* __restrict__ blocksum, int* __restrict__ blockoff) {
    int t = threadIdx.x;                   // 0..255
    int lane = t & 63;
    int wid  = t >> 6;
    int v = (t < NB2) ? blocksum[t] : 0;
    int x = v;
    #pragma unroll
    for (int off = 1; off < 64; off <<= 1) {
        int y = __shfl_up(x, off);
        if (lane >= off) x += y;
    }
    __shared__ int wsum[4];
    if (lane == 63) wsum[wid] = x;
    __syncthreads();
    int add = 0;
    #pragma unroll
    for (int i = 0; i < 4; ++i) if (i < wid) add += wsum[i];
    if (t < NB2) blockoff[t] = x + add - v;
}

__global__ void k_scan3g(int* __restrict__ excl, const int* __restrict__ blockoff) {
    int gid = blockIdx.x * blockDim.x + threadIdx.x;
    if (gid < NBB) excl[gid] += blockoff[gid >> 10];
}

__global__ void __launch_bounds__(256) k_binscatter(
        const int* __restrict__ arow, const int* __restrict__ acol,
        const float* __restrict__ aval, const int* __restrict__ bbbase,
        int2* __restrict__ tmp) {
    __shared__ int lcur[NBIN];
    int t = threadIdx.x;
    for (int i = t; i < NBIN; i += 256)
        lcur[i] = bbbase[i * SCAT_BLOCKS + blockIdx.x];
    __syncthreads();
    int s = blockIdx.x * EPB, e = s + EPB;
    for (int i = s + t; i < e; i += 256) {
        int r   = arow[i];
        int bin = r >> BIN_SHIFT;
        int off = atomicAdd(&lcur[bin], 1);          // LDS atomic
        int drow = r & (BIN_SIZE - 1);
        tmp[off] = make_int2((drow << 17) | acol[i], __float_as_int(aval[i]));
    }
}

// Per bin: LDS row-histogram + local scan -> row_ptr (coalesced) + final scatter
// into 4-byte compressed edge records.
__global__ void __launch_bounds__(256) k_binfinal(
        const int* __restrict__ bbbase, const int2* __restrict__ tmp,
        int* __restrict__ row_ptr, unsigned* __restrict__ edge_c) {
    __shared__ int hist[BIN_SIZE];                   // then reused as cursors
    __shared__ int wsum[4];
    int t = threadIdx.x;
    int bin = blockIdx.x;
    int rbase = bin << BIN_SHIFT;
    int binstart = bbbase[bin * SCAT_BLOCKS];
    int binend   = (bin + 1 < NBIN) ? bbbase[(bin + 1) * SCAT_BLOCKS] : E_EDGES;

    for (int i = t; i < BIN_SIZE; i += 256) hist[i] = 0;
    __syncthreads();
    for (int i = binstart + t; i < binend; i += 256)
        atomicAdd(&hist[((unsigned)tmp[i].x) >> 17], 1);   // LDS atomic
    __syncthreads();

    // 256-thread exclusive scan of hist[512]: each thread owns 2 elements.
    int lane = t & 63, wid = t >> 6;
    int b2 = t * 2;
    int h0 = hist[b2], h1 = hist[b2 + 1];
    int tsum = h0 + h1;
    int x = tsum;
    #pragma unroll
    for (int off = 1; off < 64; off <<= 1) {
        int y = __shfl_up(x, off);
        if (lane >= off) x += y;
    }
    if (lane == 63) wsum[wid] = x;
    __syncthreads();
    int woff = 0;
    #pragma unroll
    for (int i = 0; i < 4; ++i) if (i < wid) woff += wsum[i];
    int excl = woff + x - tsum;

    int c0 = binstart + excl;
    int c1 = c0 + h0;
    __syncthreads();
    hist[b2] = c0; hist[b2 + 1] = c1;
    if (rbase + b2     < NTOT) row_ptr[rbase + b2]     = c0;
    if (rbase + b2 + 1 < NTOT) row_ptr[rbase + b2 + 1] = c1;
    if (bin == NBIN - 1 && t == 0) row_ptr[NTOT] = E_EDGES;
    __syncthreads();

    for (int i = binstart + t; i < binend; i += 256) {
        int2 rec = tmp[i];
        int drow = ((unsigned)rec.x) >> 17;
        int pos  = atomicAdd(&hist[drow], 1);        // LDS atomic
        unsigned vb = (unsigned)rec.y;
        unsigned b  = (vb + 0x7FFFu + ((vb >> 16) & 1u)) >> 16;   // bf16 round
        edge_c[pos] = ((b & 0x7FFFu) << 17) | ((unsigned)rec.x & 0x1FFFFu);
    }
}

// ---------------------------------------------------------------------------
// SpMM (both hops), int8 in / int8 out, fp32 accumulate.
// Wave = 1 row, 8 groups of 8 lanes; group = one edge; lane loads uint2
// (8 bytes = 8 int8 values -> 64 B row per group). Per edge: one broadcast
// scale load scl[col]; decode via (float)((w>>8k)&0xff) = v_cvt_f32_ubyte;
// bias (+128) corrected once per row via bsum. Output re-quantized per-row.
// ---------------------------------------------------------------------------
__global__ void __launch_bounds__(256) spmm_q8(
        const int* __restrict__ row_ptr, const unsigned* __restrict__ edge_c,
        const unsigned char* __restrict__ srcq, const float* __restrict__ sscl,
        unsigned char* __restrict__ dstq, float* __restrict__ dscl) {
    int gtid = blockIdx.x * blockDim.x + threadIdx.x;
    int row  = gtid >> 6;
    int lane = gtid & 63;
    if (row >= NTOT) return;
    int g    = lane >> 3;         // edge slot (0..7)
    int sub  = lane & 7;          // 8-byte chunk of the 64 B row
    int s = row_ptr[row];
    int e = row_ptr[row + 1];
    float a0 = 0.f, a1 = 0.f, a2 = 0.f, a3 = 0.f;
    float a4 = 0.f, a5 = 0.f, a6 = 0.f, a7 = 0.f;
    float bs = 0.f;
    for (int base = s; base < e; base += 8) {
        int i = base + g;
        int j = (i < e) ? i : s;                     // clamp to a valid record
        unsigned rec = edge_c[j];
        unsigned col = rec & 0x1FFFFu;
        float sc = sscl[col];                        // broadcast within group
        float vs = (i < e) ? rec_val(rec) * sc : 0.0f;
        uint2 d = *reinterpret_cast<const uint2*>(srcq + ((size_t)col << 6) + sub * 8);
        a0 = fmaf(vs, (float)(d.x & 0xffu),         a0);
        a1 = fmaf(vs, (float)((d.x >> 8) & 0xffu),  a1);
        a2 = fmaf(vs, (float)((d.x >> 16) & 0xffu), a2);
        a3 = fmaf(vs, (float)(d.x >> 24),           a3);
        a4 = fmaf(vs, (float)(d.y & 0xffu),         a4);
        a5 = fmaf(vs, (float)((d.y >> 8) & 0xffu),  a5);
        a6 = fmaf(vs, (float)((d.y >> 16) & 0xffu), a6);
        a7 = fmaf(vs, (float)(d.y >> 24),           a7);
        bs += vs;
    }
    // bias correction: stored q = x/scale + 128
    a0 = fmaf(-128.f, bs, a0); a1 = fmaf(-128.f, bs, a1);
    a2 = fmaf(-128.f, bs, a2); a3 = fmaf(-128.f, bs, a3);
    a4 = fmaf(-128.f, bs, a4); a5 = fmaf(-128.f, bs, a5);
    a6 = fmaf(-128.f, bs, a6); a7 = fmaf(-128.f, bs, a7);
    // butterfly sum across the 8 edge-groups (same sub exchanges)
    #pragma unroll
    for (int off = 8; off < 64; off <<= 1) {
        a0 += __shfl_xor(a0, off); a1 += __shfl_xor(a1, off);
        a2 += __shfl_xor(a2, off); a3 += __shfl_xor(a3, off);
        a4 += __shfl_xor(a4, off); a5 += __shfl_xor(a5, off);
        a6 += __shfl_xor(a6, off); a7 += __shfl_xor(a7, off);
    }
    // row max for re-quantization (all lanes participate)
    float m = fmaxf(fmaxf(fmaxf(fabsf(a0), fabsf(a1)), fmaxf(fabsf(a2), fabsf(a3))),
                    fmaxf(fmaxf(fabsf(a4), fabsf(a5)), fmaxf(fabsf(a6), fabsf(a7))));
    #pragma unroll
    for (int off = 1; off < 8; off <<= 1) m = fmaxf(m, __shfl_xor(m, off));
    float inv = (m > 0.0f) ? 127.0f / m : 0.0f;
    if (g == 0) {
        unsigned q0 = (unsigned)fmaf(a0, inv, 128.5f);
        unsigned q1 = (unsigned)fmaf(a1, inv, 128.5f);
        unsigned q2 = (unsigned)fmaf(a2, inv, 128.5f);
        unsigned q3 = (unsigned)fmaf(a3, inv, 128.5f);
        unsigned q4 = (unsigned)fmaf(a4, inv, 128.5f);
        unsigned q5 = (unsigned)fmaf(a5, inv, 128.5f);
        unsigned q6 = (unsigned)fmaf(a6, inv, 128.5f);
        unsigned q7 = (unsigned)fmaf(a7, inv, 128.5f);
        uint2 o;
        o.x = q0 | (q1 << 8) | (q2 << 16) | (q3 << 24);
        o.y = q4 | (q5 << 8) | (q6 << 16) | (q7 << 24);
        *reinterpret_cast<uint2*>(dstq + ((size_t)row << 6) + sub * 8) = o;
        if (sub == 0) dscl[row] = m * (1.0f / 127.0f);
    }
}

// ---------------------------------------------------------------------------
// Hop-3 pull for one row over int8 src (lane = elem layout), bias-corrected.
// ---------------------------------------------------------------------------
__device__ __forceinline__ float pull_row_q(const int* __restrict__ row_ptr,
                                            const unsigned* __restrict__ edge_c,
                                            const unsigned char* __restrict__ srcq,
                                            const float* __restrict__ sscl,
                                            int row, int lane) {
    int s = row_ptr[row];
    int e = row_ptr[row + 1];
    float acc0 = 0.0f, acc1 = 0.0f, bs = 0.0f;
    for (int base = s; base < e; base += 8) {
        unsigned ed[8];
        float vs[8];
        #pragma unroll
        for (int i = 0; i < 8; ++i) {
            int idx = base + i;
            ed[i] = (idx < e) ? edge_c[idx] : 0u;
            vs[i] = (idx < e) ? rec_val(ed[i]) * sscl[ed[i] & 0x1FFFFu] : 0.0f;
        }
        float a[8];
        #pragma unroll
        for (int i = 0; i < 8; ++i)
            a[i] = (float)srcq[((size_t)(ed[i] & 0x1FFFFu) << 6) + lane];
        #pragma unroll
        for (int i = 0; i < 8; i += 2) {
            acc0 = fmaf(vs[i],     a[i],     acc0);
            acc1 = fmaf(vs[i + 1], a[i + 1], acc1);
            bs  += vs[i] + vs[i + 1];
        }
    }
    return acc0 + acc1 - 128.0f * bs;
}

// ---------------------------------------------------------------------------
// mean_rows: one wave per (batch, row-type). NO contended atomics.
// ---------------------------------------------------------------------------
__global__ void mean_rows(const unsigned char* __restrict__ side1q,
                          const float* __restrict__ scl1,
                          const unsigned char* __restrict__ side2q,
                          const float* __restrict__ scl2,
                          const int* __restrict__ row_ptr, const unsigned* __restrict__ edge_c,
                          const float* __restrict__ ge, const float* __restrict__ de,
                          const float* __restrict__ gt, const float* __restrict__ dt,
                          const int* __restrict__ user, const int* __restrict__ pos,
                          const int* __restrict__ neg, float* __restrict__ mrows,
                          float* __restrict__ regbuf) {
    int gtid = blockIdx.x * blockDim.x + threadIdx.x;
    int wave = gtid >> 6;                  // 0 .. 3*B-1
    int lane = gtid & 63;
    if (wave >= 3 * B_BATCH) return;
    int b = wave / 3;
    int j = wave - 3 * b;                  // 0=user, 1=pos, 2=neg

    int   row;
    float t, e0;
    if (j == 0) {
        int u = user[b];
        row = u;  t = gt[u];  e0 = ge[(size_t)u * DIM + lane];
    } else {
        int d = (j == 1) ? pos[b] : neg[b * K_NEG];
        row = N_G + d;  t = dt[d];  e0 = de[(size_t)d * DIM + lane];
    }
    float w0 = expf(-t);
    float w1 = w0 * t;
    float w2 = w1 * t * 0.5f;
    float w3 = w1 * t * t * (1.0f / 6.0f);

    float s1 = ((float)side1q[((size_t)row << 6) + lane] - 128.0f) * scl1[row];
    float s2 = ((float)side2q[((size_t)row << 6) + lane] - 128.0f) * scl2[row];
    float s3 = pull_row_q(row_ptr, edge_c, side2q, scl2, row, lane);
    float m  = 0.25f * (w0 * e0 + w1 * s1 + w2 * s2 + w3 * s3);
    mrows[(size_t)wave * DIM + lane] = m;

    float r0 = w0 * e0;
    float reg = r0 * r0;
    #pragma unroll
    for (int off = 32; off > 0; off >>= 1) reg += __shfl_down(reg, off);
    if (lane == 0) regbuf[wave] = reg;
}

// ---------------------------------------------------------------------------
// loss_dot: one wave per batch element; plain store of per-batch mf term.
// ---------------------------------------------------------------------------
__global__ void loss_dot(const float* __restrict__ mrows, float* __restrict__ mfbuf) {
    int gtid = blockIdx.x * blockDim.x + threadIdx.x;
    int b    = gtid >> 6;
    int lane = gtid & 63;
    if (b >= B_BATCH) return;
    float gm = mrows[(size_t)(3 * b + 0) * DIM + lane];
    float pm = mrows[(size_t)(3 * b + 1) * DIM + lane];
    float nm = mrows[(size_t)(3 * b + 2) * DIM + lane];
    float dotp = gm * pm;
    float dotn = gm * nm;
    #pragma unroll
    for (int off = 32; off > 0; off >>= 1) {
        dotp += __shfl_down(dotp, off);
        dotn += __shfl_down(dotn, off);
    }
    if (lane == 0) {
        float x = dotn - dotp;
        mfbuf[b] = fmaxf(x, 0.0f) + log1pf(expf(-fabsf(x)));   // log1p(exp(x))
    }
}

// ---------------------------------------------------------------------------
// final_reduce: single block sums regbuf (3B) + mfbuf (B), emits 3 outputs.
// ---------------------------------------------------------------------------
__global__ void final_reduce(const float* __restrict__ regbuf,
                             const float* __restrict__ mfbuf,
                             float* __restrict__ out) {
    int t    = threadIdx.x;                // 1024 threads = 16 waves
    int lane = t & 63;
    int wid  = t >> 6;
    float mf = 0.0f, rg = 0.0f;
    for (int i = t; i < B_BATCH; i += 1024)     mf += mfbuf[i];
    for (int i = t; i < 3 * B_BATCH; i += 1024) rg += regbuf[i];
    #pragma unroll
    for (int off = 32; off > 0; off >>= 1) {
        mf += __shfl_down(mf, off);
        rg += __shfl_down(rg, off);
    }
    __shared__ float smf[16], srg[16];
    if (lane == 0) { smf[wid] = mf; srg[wid] = rg; }
    __syncthreads();
    if (t == 0) {
        float M = 0.0f, R = 0.0f;
        #pragma unroll
        for (int i = 0; i < 16; ++i) { M += smf[i]; R += srg[i]; }
        float mfm = M / (float)B_BATCH;
        float emb = DECAY_F * (R * 0.5f) / (float)B_BATCH;
        out[0] = mfm + emb;
        out[1] = mfm;
        out[2] = emb;
    }
}

extern "C" void kernel_launch(void* const* d_in, const int* in_sizes, int n_in,
                              void* d_out, int out_size, void* d_ws, size_t ws_size,
                              hipStream_t stream) {
    const float* ge   = (const float*)d_in[0];
    const float* de   = (const float*)d_in[1];
    const float* gt   = (const float*)d_in[2];
    const float* dt   = (const float*)d_in[3];
    const float* aval = (const float*)d_in[4];
    const int*   arow = (const int*)d_in[5];
    const int*   acol = (const int*)d_in[6];
    const int*   user = (const int*)d_in[7];
    const int*   pos  = (const int*)d_in[8];
    const int*   neg  = (const int*)d_in[9];
    float* out = (float*)d_out;

    // Workspace layout (~47 MB)
    char* ws = (char*)d_ws;
    const size_t rowQBytes = (size_t)NTOT * DIM;                 // 6.4 MB
    unsigned char* rawq   = (unsigned char*)(ws);
    unsigned char* side1q = (unsigned char*)(ws + rowQBytes);
    unsigned char* side2q = (unsigned char*)(ws + 2 * rowQBytes);
    char* p = ws + 3 * rowQBytes;
    float*    scl0    = (float*)p;         p += (size_t)NTOT * sizeof(float);
    float*    scl1    = (float*)p;         p += (size_t)NTOT * sizeof(float);
    float*    scl2    = (float*)p;         p += (size_t)NTOT * sizeof(float);
    int2*     tmp     = (int2*)p;          p += (size_t)E_EDGES * sizeof(int2);
    unsigned* edge_c  = (unsigned*)p;      p += (size_t)E_EDGES * sizeof(unsigned);
    float*    mrows   = (float*)p;         p += (size_t)3 * B_BATCH * DIM * sizeof(float);
    int*      row_ptr = (int*)p;           p += (NTOT + 1) * sizeof(int);
    int*      bbcnt   = (int*)p;           p += (size_t)NBB * sizeof(int);
    int*      bbbase  = (int*)p;           p += (size_t)NBB * sizeof(int);
    int*      blocksum= (int*)p;           p += 256 * sizeof(int);
    int*      blockoff= (int*)p;           p += 256 * sizeof(int);
    float*    regbuf  = (float*)p;         p += (size_t)3 * B_BATCH * sizeof(float);
    float*    mfbuf   = (float*)p;

    conv_q<<<(NTOT * 64 + 255) / 256, 256, 0, stream>>>(ge, de, rawq, scl0);

    // CSR build — no global atomics anywhere.
    k_hist1     <<<SCAT_BLOCKS, 256, 0, stream>>>(arow, bbcnt);
    k_scan1g    <<<NB2, 1024, 0, stream>>>(bbcnt, bbbase, blocksum);
    k_scan2g    <<<1, 256, 0, stream>>>(blocksum, blockoff);
    k_scan3g    <<<(NBB + 255) / 256, 256, 0, stream>>>(bbbase, blockoff);
    k_binscatter<<<SCAT_BLOCKS, 256, 0, stream>>>(arow, acol, aval, bbbase, tmp);
    k_binfinal  <<<NBIN, 256, 0, stream>>>(bbbase, tmp, row_ptr, edge_c);

    const int spmm_blocks = (NTOT * 64 + 255) / 256;
    spmm_q8<<<spmm_blocks, 256, 0, stream>>>(row_ptr, edge_c, rawq,   scl0, side1q, scl1);
    spmm_q8<<<spmm_blocks, 256, 0, stream>>>(row_ptr, edge_c, side1q, scl1, side2q, scl2);

    mean_rows<<<(3 * B_BATCH * 64 + 255) / 256, 256, 0, stream>>>(
        side1q, scl1, side2q, scl2, row_ptr, edge_c, ge, de, gt, dt,
        user, pos, neg, mrows, regbuf);
    loss_dot<<<(B_BATCH * 64 + 255) / 256, 256, 0, stream>>>(mrows, mfbuf);
    final_reduce<<<1, 1024, 0, stream>>>(regbuf, mfbuf, out);
}